// Round 1
// 195.187 us; speedup vs baseline: 1.4512x; 1.4512x over previous
//
#include <hip/hip_runtime.h>
#include <hip/hip_bf16.h>

#define BB 2
#define PP 128
#define CC 8
#define EE 1024
#define HH 16
#define KVHH 4
#define DD 64
#define TT 1024
#define EKVV 256

typedef unsigned short u16;
typedef unsigned int u32;
typedef __attribute__((ext_vector_type(8))) short bf16x8;
typedef __attribute__((ext_vector_type(4))) float f32x4;

__device__ __forceinline__ float b2f(u16 u) {
    u32 x = ((u32)u) << 16;
    return __uint_as_float(x);
}
__device__ __forceinline__ u16 f2b(float f) {
    u32 x = __float_as_uint(f);
    u32 r = (x + 0x7FFFu + ((x >> 16) & 1u)) >> 16;
    return (u16)r;
}

// async global->LDS 16B (wave-uniform LDS base + lane*16 layout required)
#define GLL16(gp, lp)                                                          \
    __builtin_amdgcn_global_load_lds(                                          \
        (__attribute__((address_space(1))) void*)(gp),                         \
        (__attribute__((address_space(3))) void*)(lp), 16, 0, 0)

// ---------------------------------------------------------------------------
// k_prep: one-time conversions.
//   blocks [0,1024):    hidden f32 -> bf16 (hb), linear
//   blocks [1024,2048): Wq   1024x1024 -> btq rows [0,1024)    (transposed bf16)
//   blocks [2048,2560): Wkv  1024x512  -> btq rows [1024,1536) (transposed bf16)
//   blocks [2560,3584): Wproj 1024x1024 -> btp                 (transposed bf16)
// ---------------------------------------------------------------------------
__global__ __launch_bounds__(256) void k_prep(const float* __restrict__ hidden,
                                              const float* __restrict__ Wq,
                                              const float* __restrict__ Wkv,
                                              const float* __restrict__ Wproj,
                                              u16* __restrict__ hb,
                                              u16* __restrict__ btq,
                                              u16* __restrict__ btp) {
    __shared__ float ts[32][33];
    int bid = blockIdx.x;
    int tid = threadIdx.x;
    if (bid < 1024) {
        int base = (bid * 256 + tid) * 8;
        float4 a0 = *(const float4*)(hidden + base);
        float4 a1 = *(const float4*)(hidden + base + 4);
        u16 o[8] = {f2b(a0.x), f2b(a0.y), f2b(a0.z), f2b(a0.w),
                    f2b(a1.x), f2b(a1.y), f2b(a1.z), f2b(a1.w)};
        *(uint4*)(hb + base) = *(uint4*)o;
        return;
    }
    bid -= 1024;
    const float* W;
    u16* out;
    int N, tk, tn;
    if (bid < 1024) {
        W = Wq; out = btq; N = 1024; tk = bid >> 5; tn = bid & 31;
    } else if (bid < 1536) {
        int b2 = bid - 1024;
        W = Wkv; out = btq + 1024 * 1024; N = 512; tk = b2 >> 4; tn = b2 & 15;
    } else {
        int b2 = bid - 1536;
        W = Wproj; out = btp; N = 1024; tk = b2 >> 5; tn = b2 & 31;
    }
    int r = tid >> 3, c4 = (tid & 7) << 2;
    float4 v = *(const float4*)(W + (size_t)(tk * 32 + r) * N + tn * 32 + c4);
    ts[r][c4 + 0] = v.x;
    ts[r][c4 + 1] = v.y;
    ts[r][c4 + 2] = v.z;
    ts[r][c4 + 3] = v.w;
    __syncthreads();
    u16 o[4] = {f2b(ts[c4 + 0][r]), f2b(ts[c4 + 1][r]),
                f2b(ts[c4 + 2][r]), f2b(ts[c4 + 3][r])};
    *(ushort4*)(out + (size_t)(tn * 32 + r) * 1024 + tk * 32 + c4) = *(ushort4*)o;
}

// ---------------------------------------------------------------------------
// sgemm_sk: split-K GEMM for the two tiny projections (unchanged).
// ---------------------------------------------------------------------------
__global__ __launch_bounds__(256) void sgemm_sk(const float* __restrict__ pos,
                                                const float* __restrict__ Wpos,
                                                const float* __restrict__ chan,
                                                const float* __restrict__ Wchan,
                                                float* __restrict__ tkb,
                                                float* __restrict__ ckb) {
    __shared__ float As[16][68];
    __shared__ float Bs[16][68];
    int tile = blockIdx.x;
    const float* A; const float* B; float* C; int M, m0, n0;
    if (tile < 8) { A = pos;  B = Wpos;  C = tkb; M = 128; m0 = (tile >> 2) * 64; n0 = (tile & 3) * 64; }
    else          { A = chan; B = Wchan; C = ckb; M = 8;   m0 = 0;               n0 = (tile - 8) * 64; }
    int kbase = blockIdx.y * 128;

    int tid = threadIdx.x;
    int tx = tid & 15, ty = tid >> 4;
    float acc[4][4];
#pragma unroll
    for (int r = 0; r < 4; r++)
#pragma unroll
        for (int c = 0; c < 4; c++) acc[r][c] = 0.f;

    int am = tid >> 2, ak = (tid & 3) << 2;
    int bk = tid >> 4, bn = (tid & 15) << 2;

    for (int k0 = kbase; k0 < kbase + 128; k0 += 16) {
        int row = m0 + am;
        float4 av;
        if (row < M) av = *reinterpret_cast<const float4*>(A + (size_t)row * 1024 + k0 + ak);
        else av = make_float4(0.f, 0.f, 0.f, 0.f);
        As[ak + 0][am] = av.x;
        As[ak + 1][am] = av.y;
        As[ak + 2][am] = av.z;
        As[ak + 3][am] = av.w;
        float4 bv = *reinterpret_cast<const float4*>(B + (size_t)(k0 + bk) * 256 + n0 + bn);
        Bs[bk][bn + 0] = bv.x;
        Bs[bk][bn + 1] = bv.y;
        Bs[bk][bn + 2] = bv.z;
        Bs[bk][bn + 3] = bv.w;
        __syncthreads();
#pragma unroll
        for (int kk = 0; kk < 16; kk++) {
            float4 a4 = *reinterpret_cast<const float4*>(&As[kk][ty << 2]);
            float4 b4 = *reinterpret_cast<const float4*>(&Bs[kk][tx << 2]);
            acc[0][0] += a4.x * b4.x; acc[0][1] += a4.x * b4.y; acc[0][2] += a4.x * b4.z; acc[0][3] += a4.x * b4.w;
            acc[1][0] += a4.y * b4.x; acc[1][1] += a4.y * b4.y; acc[1][2] += a4.y * b4.z; acc[1][3] += a4.y * b4.w;
            acc[2][0] += a4.z * b4.x; acc[2][1] += a4.z * b4.y; acc[2][2] += a4.z * b4.z; acc[2][3] += a4.z * b4.w;
            acc[3][0] += a4.w * b4.x; acc[3][1] += a4.w * b4.y; acc[3][2] += a4.w * b4.z; acc[3][3] += a4.w * b4.w;
        }
        __syncthreads();
    }
#pragma unroll
    for (int r = 0; r < 4; r++) {
        int row = m0 + (ty << 2) + r;
        if (row < M) {
#pragma unroll
            for (int c = 0; c < 4; c++) {
                int col = n0 + (tx << 2) + c;
                atomicAdd(&C[(size_t)row * 256 + col], acc[r][c]);
            }
        }
    }
}

// ---------------------------------------------------------------------------
// mgemm_qkv2: m97-structure bf16 GEMM (global_load_lds + 2-phase dbuf).
// A = hb [2048][1024] bf16, B = btq [1536][1024] bf16 (row = output col).
// ---------------------------------------------------------------------------
__global__ __launch_bounds__(256) void mgemm_qkv2(const u16* __restrict__ Ab,
                                                  const u16* __restrict__ BT,
                                                  u16* __restrict__ qout,
                                                  u16* __restrict__ kvout) {
    __shared__ __align__(16) u16 As[2][128 * 32];
    __shared__ __align__(16) u16 Bs[2][128 * 32];
    int tid = threadIdx.x;
    int ntile = blockIdx.x;
    int m0 = blockIdx.y * 128;
    int n0g = ntile * 128;
    u16* Cout; int BN, n0;
    if (ntile < 8) { Cout = qout;  BN = 1024; n0 = n0g; }
    else           { Cout = kvout; BN = 512;  n0 = n0g - 1024; }

    int lane = tid & 63, wave = tid >> 6;
    int r16 = lane & 15, quad = lane >> 4;
    int mb = (wave >> 1) * 64, nb = (wave & 1) * 64;
    int srow = tid >> 2, skg = (tid & 3) << 3;

#define STAGE_QKV(buf, k0)                                                         \
    do {                                                                           \
        GLL16(Ab + (size_t)(m0 + srow) * 1024 + (k0) + skg,      As[buf] + tid * 8);        \
        GLL16(Ab + (size_t)(m0 + srow + 64) * 1024 + (k0) + skg, As[buf] + (tid + 256) * 8);\
        GLL16(BT + (size_t)(n0g + srow) * 1024 + (k0) + skg,      Bs[buf] + tid * 8);       \
        GLL16(BT + (size_t)(n0g + srow + 64) * 1024 + (k0) + skg, Bs[buf] + (tid + 256) * 8);\
    } while (0)

    f32x4 acc[4][4];
#pragma unroll
    for (int mt = 0; mt < 4; mt++)
#pragma unroll
        for (int nt = 0; nt < 4; nt++) acc[mt][nt] = (f32x4){0.f, 0.f, 0.f, 0.f};

    STAGE_QKV(0, 0);
    __syncthreads();
    int cur = 0;
    for (int k0 = 0; k0 < 1024; k0 += 32) {
        if (k0 + 32 < 1024) STAGE_QKV(cur ^ 1, k0 + 32);
        bf16x8 af[4], bfr[4];
#pragma unroll
        for (int mt = 0; mt < 4; mt++)
            af[mt] = *(const bf16x8*)(As[cur] + (mb + mt * 16 + r16) * 32 + quad * 8);
#pragma unroll
        for (int nt = 0; nt < 4; nt++)
            bfr[nt] = *(const bf16x8*)(Bs[cur] + (nb + nt * 16 + r16) * 32 + quad * 8);
#pragma unroll
        for (int mt = 0; mt < 4; mt++)
#pragma unroll
            for (int nt = 0; nt < 4; nt++)
                acc[mt][nt] = __builtin_amdgcn_mfma_f32_16x16x32_bf16(af[mt], bfr[nt], acc[mt][nt], 0, 0, 0);
        __syncthreads();
        cur ^= 1;
    }
#pragma unroll
    for (int mt = 0; mt < 4; mt++)
#pragma unroll
        for (int nt = 0; nt < 4; nt++)
#pragma unroll
            for (int rg = 0; rg < 4; rg++) {
                int row = m0 + mb + mt * 16 + quad * 4 + rg;
                int col = n0 + nb + nt * 16 + r16;
                Cout[(size_t)row * BN + col] = f2b(acc[mt][nt][rg]);
            }
#undef STAGE_QKV
}

// ---------------------------------------------------------------------------
// mgemm_proj2: same structure, A = A2 bf16, B = btp, fp32 output.
// ---------------------------------------------------------------------------
__global__ __launch_bounds__(256) void mgemm_proj2(const u16* __restrict__ Ab,
                                                   const u16* __restrict__ BT,
                                                   float* __restrict__ Cf) {
    __shared__ __align__(16) u16 As[2][128 * 32];
    __shared__ __align__(16) u16 Bs[2][128 * 32];
    int tid = threadIdx.x;
    int n0 = blockIdx.x * 128;
    int m0 = blockIdx.y * 128;

    int lane = tid & 63, wave = tid >> 6;
    int r16 = lane & 15, quad = lane >> 4;
    int mb = (wave >> 1) * 64, nb = (wave & 1) * 64;
    int srow = tid >> 2, skg = (tid & 3) << 3;

#define STAGE_PRJ(buf, k0)                                                         \
    do {                                                                           \
        GLL16(Ab + (size_t)(m0 + srow) * 1024 + (k0) + skg,      As[buf] + tid * 8);        \
        GLL16(Ab + (size_t)(m0 + srow + 64) * 1024 + (k0) + skg, As[buf] + (tid + 256) * 8);\
        GLL16(BT + (size_t)(n0 + srow) * 1024 + (k0) + skg,      Bs[buf] + tid * 8);        \
        GLL16(BT + (size_t)(n0 + srow + 64) * 1024 + (k0) + skg, Bs[buf] + (tid + 256) * 8);\
    } while (0)

    f32x4 acc[4][4];
#pragma unroll
    for (int mt = 0; mt < 4; mt++)
#pragma unroll
        for (int nt = 0; nt < 4; nt++) acc[mt][nt] = (f32x4){0.f, 0.f, 0.f, 0.f};

    STAGE_PRJ(0, 0);
    __syncthreads();
    int cur = 0;
    for (int k0 = 0; k0 < 1024; k0 += 32) {
        if (k0 + 32 < 1024) STAGE_PRJ(cur ^ 1, k0 + 32);
        bf16x8 af[4], bfr[4];
#pragma unroll
        for (int mt = 0; mt < 4; mt++)
            af[mt] = *(const bf16x8*)(As[cur] + (mb + mt * 16 + r16) * 32 + quad * 8);
#pragma unroll
        for (int nt = 0; nt < 4; nt++)
            bfr[nt] = *(const bf16x8*)(Bs[cur] + (nb + nt * 16 + r16) * 32 + quad * 8);
#pragma unroll
        for (int mt = 0; mt < 4; mt++)
#pragma unroll
            for (int nt = 0; nt < 4; nt++)
                acc[mt][nt] = __builtin_amdgcn_mfma_f32_16x16x32_bf16(af[mt], bfr[nt], acc[mt][nt], 0, 0, 0);
        __syncthreads();
        cur ^= 1;
    }
#pragma unroll
    for (int mt = 0; mt < 4; mt++)
#pragma unroll
        for (int nt = 0; nt < 4; nt++)
#pragma unroll
            for (int rg = 0; rg < 4; rg++) {
                int row = m0 + mb + mt * 16 + quad * 4 + rg;
                int col = n0 + nb + nt * 16 + r16;
                Cf[(size_t)row * 1024 + col] = acc[mt][nt][rg];
            }
#undef STAGE_PRJ
}

// ---------------------------------------------------------------------------
// mk_ta: MFMA time_att with fused rel-shift scatter (unchanged).
// ---------------------------------------------------------------------------
__global__ __launch_bounds__(256) void mk_ta(const u16* __restrict__ qb,
                                             const float* __restrict__ tkb,
                                             const float* __restrict__ bias,
                                             u16* __restrict__ tsb) {
    __shared__ __align__(16) u16 qs[128 * 72];
    __shared__ __align__(16) u16 tks[128 * 72];
    int tid = threadIdx.x;
    int t0 = blockIdx.x * 128;
    int h = blockIdx.y, b = blockIdx.z;
    int kvh = h >> 2;

#pragma unroll
    for (int it = 0; it < 4; it++) {
        int idx = tid + it * 256;
        int r = idx >> 3, dg = (idx & 7) << 3;
        uint4 u = *(const uint4*)(qb + ((size_t)(b * TT + t0 + r)) * EE + h * 64 + dg);
        u16 tmp[8]; *(uint4*)tmp = u;
        u16 outv[8];
#pragma unroll
        for (int j = 0; j < 8; j++) outv[j] = f2b(b2f(tmp[j]) + bias[EKVV + kvh * 64 + dg + j]);
        *(uint4*)(qs + r * 72 + dg) = *(uint4*)outv;
    }
#pragma unroll
    for (int it = 0; it < 4; it++) {
        int idx = tid + it * 256;
        int p = idx >> 3, dg = (idx & 7) << 3;
        const float* tp = tkb + p * EKVV + kvh * 64 + dg;
        float4 a0 = *(const float4*)(tp);
        float4 a1 = *(const float4*)(tp + 4);
        u16 outv[8] = {f2b(a0.x), f2b(a0.y), f2b(a0.z), f2b(a0.w),
                       f2b(a1.x), f2b(a1.y), f2b(a1.z), f2b(a1.w)};
        *(uint4*)(tks + p * 72 + dg) = *(uint4*)outv;
    }
    __syncthreads();

    int lane = tid & 63, wave = tid >> 6;
    int r16 = lane & 15, quad = lane >> 4;
    int mb = (wave >> 1) * 64, nb = (wave & 1) * 64;

    f32x4 acc[4][4];
#pragma unroll
    for (int mt = 0; mt < 4; mt++)
#pragma unroll
        for (int nt = 0; nt < 4; nt++) acc[mt][nt] = (f32x4){0.f, 0.f, 0.f, 0.f};

#pragma unroll
    for (int k0 = 0; k0 < 64; k0 += 32) {
        bf16x8 af[4], bfr[4];
#pragma unroll
        for (int mt = 0; mt < 4; mt++)
            af[mt] = *(const bf16x8*)(qs + (mb + mt * 16 + r16) * 72 + k0 + quad * 8);
#pragma unroll
        for (int nt = 0; nt < 4; nt++)
            bfr[nt] = *(const bf16x8*)(tks + (nb + nt * 16 + r16) * 72 + k0 + quad * 8);
#pragma unroll
        for (int mt = 0; mt < 4; mt++)
#pragma unroll
            for (int nt = 0; nt < 4; nt++)
                acc[mt][nt] = __builtin_amdgcn_mfma_f32_16x16x32_bf16(af[mt], bfr[nt], acc[mt][nt], 0, 0, 0);
    }

    size_t basebh = ((size_t)(b * HH + h)) * (TT * PP);
#pragma unroll
    for (int mt = 0; mt < 4; mt++)
#pragma unroll
        for (int nt = 0; nt < 4; nt++)
#pragma unroll
            for (int rg = 0; rg < 4; rg++) {
                int tp = t0 + mb + mt * 16 + quad * 4 + rg;
                int ppx = nb + nt * 16 + r16;
                int o = tp * PP + (tp >> 3) + 1 - PP + ppx;
                if (o >= 0) tsb[basebh + o] = f2b(acc[mt][nt][rg]);
            }
    if (blockIdx.x == 0 && tid < 127) {
        int tp = tid + 1;
        tsb[basebh + 1025 * tp - PP] = 0;
    }
}

// ---------------------------------------------------------------------------
// k_vt: V transpose (unchanged).
// ---------------------------------------------------------------------------
__global__ __launch_bounds__(256) void k_vt(const u16* __restrict__ kvb,
                                            u16* __restrict__ vt) {
    int k = blockIdx.x * 256 + threadIdx.x;  // < 524288
    int s = k & 1023, d = (k >> 10) & 63, kvh = (k >> 16) & 3, b = k >> 18;
    vt[k] = kvb[((size_t)(b * TT + s)) * (2 * EKVV) + EKVV + kvh * 64 + d];
}

// ---------------------------------------------------------------------------
// k_att4: big-tile MFMA flash attention. Only change: g remap so that the two
// blocks co-resident on a CU (i and i+256 under round-robin dispatch) carry
// complementary chunk counts (work-balance the tail).
// ---------------------------------------------------------------------------
__global__ __launch_bounds__(256) void k_att4(const u16* __restrict__ qb,
                                              const u16* __restrict__ kvb,
                                              const u16* __restrict__ vt,
                                              const u16* __restrict__ tsb,
                                              const float* __restrict__ ckb,
                                              const float* __restrict__ bias,
                                              u16* __restrict__ A2) {
    __shared__ __align__(16) char smem[54016];
    u16*   qg   = (u16*)(smem);              // [64][72] bf16 (q + gb)
    u16*   KP   = (u16*)(smem + 9216);       // Kst [128][72] | P [64][136]
    u16*   Vst  = (u16*)(smem + 27648);      // [64][138] bf16 (d-major)
    float* tsA  = (float*)(smem + 45312);    // [64][17] chunk time-shift
    float* csA  = (float*)(smem + 49664);    // [64][8] chan scores
    float* cks  = (float*)(smem + 51712);    // [8][64] ck rows
    float* cbmg = (float*)(smem + 53760);    // [64] cb - gb

    int tid = threadIdx.x;
    int lane = tid & 63, wave = tid >> 6;
    int r16 = lane & 15, quad = lane >> 4;
    int gx = blockIdx.x, h = blockIdx.y, b = blockIdx.z;
    int g = ((h ^ b) & 1) ? (15 - gx) : gx;
    int kvh = h >> 2;
    int t0 = g * 64;

#pragma unroll
    for (int i = 0; i < 2; i++) {
        int idx = tid + i * 256;
        int row = idx >> 3, dg = (idx & 7) << 3;
        uint4 u = *(const uint4*)(qb + ((size_t)(b * TT + t0 + row)) * EE + h * 64 + dg);
        u16 tmp[8]; *(uint4*)tmp = u;
        u16 o[8];
#pragma unroll
        for (int j = 0; j < 8; j++) o[j] = f2b(b2f(tmp[j]) + bias[kvh * 64 + dg + j]);
        *(uint4*)(qg + row * 72 + dg) = *(uint4*)o;
    }
    if (tid < 64) cbmg[tid] = bias[2 * EKVV + kvh * 64 + tid] - bias[kvh * 64 + tid];
#pragma unroll
    for (int i = 0; i < 2; i++) {
        int idx = tid + i * 256;
        cks[idx] = ckb[(idx >> 6) * EKVV + kvh * 64 + (idx & 63)];
    }
    __syncthreads();

    {
        int row = tid >> 2, cA = (tid & 3) << 1;
        int rm8 = row & 7;
        int d0 = rm8 - cA;       if (d0 < 0) d0 = -d0;
        int d1 = rm8 - (cA + 1); if (d1 < 0) d1 = -d1;
        const float* k0p = cks + (7 - d0) * 64;
        const float* k1p = cks + (7 - d1) * 64;
        float a0 = 0.f, a1 = 0.f;
#pragma unroll 8
        for (int d = 0; d < 64; d++) {
            float qv = b2f(qg[row * 72 + d]) + cbmg[d];
            a0 += qv * k0p[d];
            a1 += qv * k1p[d];
        }
        csA[row * 8 + cA] = a0;
        csA[row * 8 + cA + 1] = a1;
    }

    bf16x8 aq0 = *(const bf16x8*)(qg + (wave * 16 + r16) * 72 + quad * 8);
    bf16x8 aq1 = *(const bf16x8*)(qg + (wave * 16 + r16) * 72 + 32 + quad * 8);

    float m[4], l[4];
    f32x4 accv[4];
#pragma unroll
    for (int rg = 0; rg < 4; rg++) { m[rg] = -1.0e30f; l[rg] = 0.f; }
#pragma unroll
    for (int nt = 0; nt < 4; nt++) accv[nt] = (f32x4){0.f, 0.f, 0.f, 0.f};

    int rowbase = wave * 16 + quad * 4;
    int nch = (g + 2) >> 1;

    for (int ci = 0; ci < nch; ci++) {
        int c0 = ci * 128;
        bool needK = (g == 15) || (c0 + 128 > g * 64 - 80);
        __syncthreads();
        {
            const u16* vsrc = vt + ((size_t)(b * KVHH + kvh)) * DD * TT + c0;
#pragma unroll
            for (int i = 0; i < 4; i++) {
                int idx = tid + i * 256;
                int d = idx >> 4, sg = (idx & 15) << 3;
                *(uint4*)(Vst + d * 138 + sg) = *(const uint4*)(vsrc + (size_t)d * TT + sg);
            }
        }
        if (tid < 128) {
            int row = tid >> 1, half = (tid & 1) << 3;
            const u16* tp = tsb + ((size_t)(b * HH + h)) * (TT * PP)
                          + (size_t)(t0 + row) * PP + (c0 >> 3) + half;
            uint4 u = *(const uint4*)tp;
            u16 tmp[8]; *(uint4*)tmp = u;
#pragma unroll
            for (int j = 0; j < 8; j++) tsA[row * 17 + half + j] = b2f(tmp[j]);
        }
        if (needK) {
#pragma unroll
            for (int i = 0; i < 4; i++) {
                int idx = tid + i * 256;
                int s = idx >> 3, dg = (idx & 7) << 3;
                *(uint4*)(KP + s * 72 + dg) =
                    *(const uint4*)(kvb + ((size_t)(b * TT + c0 + s)) * (2 * EKVV) + kvh * 64 + dg);
            }
        }
        __syncthreads();

        f32x4 sc[8];
        if (needK) {
#pragma unroll
            for (int nt = 0; nt < 8; nt++) {
                const u16* kp = KP + (nt * 16 + r16) * 72 + quad * 8;
                bf16x8 b0 = *(const bf16x8*)(kp);
                bf16x8 b1 = *(const bf16x8*)(kp + 32);
                f32x4 a = {0.f, 0.f, 0.f, 0.f};
                a = __builtin_amdgcn_mfma_f32_16x16x32_bf16(aq0, b0, a, 0, 0, 0);
                a = __builtin_amdgcn_mfma_f32_16x16x32_bf16(aq1, b1, a, 0, 0, 0);
                sc[nt] = a;
            }
        } else {
#pragma unroll
            for (int nt = 0; nt < 8; nt++) sc[nt] = (f32x4){0.f, 0.f, 0.f, 0.f};
        }

#pragma unroll
        for (int nt = 0; nt < 8; nt++) {
            int s = c0 + nt * 16 + r16;
            int spi = s >> 3;
#pragma unroll
            for (int rg = 0; rg < 4; rg++) {
                int rloc = rowbase + rg;
                int rpi = (t0 + rloc) >> 3;
                float ts = tsA[rloc * 17 + 2 * nt + (r16 >> 3)];
                float cs = csA[rloc * 8 + (r16 & 7)];
                bool win = (rpi == 127) || (rpi - spi <= 10);
                float scv = ((win ? sc[nt][rg] : 0.f) + ts + cs) * 0.125f;
                sc[nt][rg] = (spi <= rpi) ? scv : -1.0e30f;
            }
        }

        float cm[4], alpha[4], psum[4];
#pragma unroll
        for (int rg = 0; rg < 4; rg++) {
            float v = sc[0][rg];
#pragma unroll
            for (int nt = 1; nt < 8; nt++) v = fmaxf(v, sc[nt][rg]);
#pragma unroll
            for (int off = 1; off < 16; off <<= 1) v = fmaxf(v, __shfl_xor(v, off));
            float mn = fmaxf(m[rg], v);
            alpha[rg] = __expf(m[rg] - mn);
            m[rg] = mn;
            cm[rg] = mn;
        }
#pragma unroll
        for (int rg = 0; rg < 4; rg++) psum[rg] = 0.f;
#pragma unroll
        for (int nt = 0; nt < 8; nt++)
#pragma unroll
            for (int rg = 0; rg < 4; rg++) {
                float e = __expf(sc[nt][rg] - cm[rg]);
                sc[nt][rg] = e;
                psum[rg] += e;
            }
#pragma unroll
        for (int rg = 0; rg < 4; rg++) {
#pragma unroll
            for (int off = 1; off < 16; off <<= 1) psum[rg] += __shfl_xor(psum[rg], off);
            l[rg] = l[rg] * alpha[rg] + psum[rg];
        }
#pragma unroll
        for (int nt = 0; nt < 4; nt++)
#pragma unroll
            for (int rg = 0; rg < 4; rg++) accv[nt][rg] *= alpha[rg];

        __syncthreads();
#pragma unroll
        for (int nt = 0; nt < 8; nt++)
#pragma unroll
            for (int rg = 0; rg < 4; rg++)
                KP[(rowbase + rg) * 136 + nt * 16 + r16] = f2b(sc[nt][rg]);
        __syncthreads();

#pragma unroll
        for (int ks = 0; ks < 4; ks++) {
            bf16x8 ap = *(const bf16x8*)(KP + (wave * 16 + r16) * 136 + ks * 32 + quad * 8);
#pragma unroll
            for (int nt = 0; nt < 4; nt++) {
                bf16x8 bv = *(const bf16x8*)(Vst + (nt * 16 + r16) * 138 + ks * 32 + quad * 8);
                accv[nt] = __builtin_amdgcn_mfma_f32_16x16x32_bf16(ap, bv, accv[nt], 0, 0, 0);
            }
        }
    }

#pragma unroll
    for (int nt = 0; nt < 4; nt++)
#pragma unroll
        for (int rg = 0; rg < 4; rg++) {
            int rt = t0 + rowbase + rg;
            A2[((size_t)(b * TT + rt)) * EE + h * 64 + nt * 16 + r16] =
                f2b(accv[nt][rg] / l[rg]);
        }
}

extern "C" void kernel_launch(void* const* d_in, const int* in_sizes, int n_in,
                              void* d_out, int out_size, void* d_ws, size_t ws_size,
                              hipStream_t stream) {
    const float* hidden = (const float*)d_in[0];
    const float* pos    = (const float*)d_in[1];
    const float* chan   = (const float*)d_in[2];
    const float* Wq     = (const float*)d_in[3];
    const float* Wkv    = (const float*)d_in[4];
    const float* Wpos   = (const float*)d_in[5];
    const float* Wchan  = (const float*)d_in[6];
    const float* Wproj  = (const float*)d_in[7];
    const float* bias   = (const float*)d_in[8];

    // workspace carve: ~28.2 MB total
    u16* qb    = (u16*)d_ws;               // 2,097,152 u16 (4 MB)
    u16* kvb   = qb + 2097152;             // 1,048,576 u16 (2 MB)
    u16* tsb   = kvb + 1048576;            // 4,194,304 u16 (8 MB)
    u16* A2    = tsb + 4194304;            // 2,097,152 u16 (4 MB)
    u16* vt    = A2 + 2097152;             //   524,288 u16 (1 MB)
    u16* hb    = vt + 524288;              // 2,097,152 u16 (4 MB) hidden bf16
    u16* btq   = hb + 2097152;             // 1,572,864 u16 (3 MB) [Wq;Wkv]^T bf16
    u16* btp   = btq + 1572864;            // 1,048,576 u16 (2 MB) Wproj^T bf16
    float* tkb = (float*)(btp + 1048576);  //    32,768 f32 (128 KB)
    float* ckb = tkb + 32768;              //     2,048 f32 (8 KB)

    dim3 blk(256);
    // zero the split-K accumulation buffers (tkb,ckb contiguous)
    hipMemsetAsync(tkb, 0, (32768 + 2048) * sizeof(float), stream);
    // one-time bf16 conversions + weight transposes
    k_prep<<<3584, blk, 0, stream>>>(hidden, Wq, Wkv, Wproj, hb, btq, btp);
    // tiny projections via split-K (pos + chan in one dispatch)
    sgemm_sk<<<dim3(12, 8), blk, 0, stream>>>(pos, Wpos, chan, Wchan, tkb, ckb);
    // fused q/kv projection via MFMA (m97 structure)
    mgemm_qkv2<<<dim3(12, 16), blk, 0, stream>>>(hb, btq, qb, kvb);
    // V transpose
    k_vt<<<2048, blk, 0, stream>>>(kvb, vt);
    // MFMA time_att with fused rel-shift scatter -> tsb (bf16)
    mk_ta<<<dim3(8, 16, 2), blk, 0, stream>>>(qb, tkb, bias, tsb);
    // big-tile MFMA flash attention -> A2 (bf16)
    k_att4<<<dim3(16, 16, 2), blk, 0, stream>>>(qb, kvb, vt, tsb, ckb, bias, A2);
    // output projection via MFMA -> fp32 d_out
    mgemm_proj2<<<dim3(8, 16), blk, 0, stream>>>(A2, btp, (float*)d_out);
}